// Round 9
// baseline (4278.009 us; speedup 1.0000x reference)
//
#include <hip/hip_runtime.h>
#include <hip/hip_bf16.h>
#include <cstdint>

#define DMODEL 768
#define NB 64
#define NHEAD 12
#define DHEAD 64
#define SEQLEN 512
#define NDOM 3
#define NBLK 2
#define FFNH 3072
#define NBROWS (NDOM*NB)   // 192
#define NCH 8              // 64-row chunks
#define ROWCH 64
#define NBLOCKS 256
#define NTHREADS 1024

typedef __attribute__((ext_vector_type(8))) short short8;
typedef __attribute__((ext_vector_type(4))) float f32x4;

__device__ __forceinline__ float wsum64(float v){
  #pragma unroll
  for (int o = 32; o; o >>= 1) v += __shfl_xor(v, o, 64);
  return v;
}
__device__ __forceinline__ float dot4f(float4 a, float4 b){
  return fmaf(a.x, b.x, fmaf(a.y, b.y, fmaf(a.z, b.z, a.w * b.w)));
}
__device__ __forceinline__ uint32_t bfpair(float lo, float hi){
  uint32_t ul = __float_as_uint(lo), uh = __float_as_uint(hi);
  ul = (ul + 0x7FFFu + ((ul >> 16) & 1u)) >> 16;
  uh = (uh + 0x7FFFu + ((uh >> 16) & 1u)) & 0xFFFF0000u;
  return ul | uh;
}

// ---- software grid barrier (all NBLOCKS co-resident by construction) ----
__device__ __forceinline__ void gbar(int* cnt, int* gen){
  __syncthreads();
  if (threadIdx.x == 0){
    __threadfence();
    int g = __hip_atomic_load(gen, __ATOMIC_RELAXED, __HIP_MEMORY_SCOPE_AGENT);
    int v = __hip_atomic_fetch_add(cnt, 1, __ATOMIC_ACQ_REL, __HIP_MEMORY_SCOPE_AGENT);
    if (v == NBLOCKS - 1){
      __hip_atomic_store(cnt, 0, __ATOMIC_RELAXED, __HIP_MEMORY_SCOPE_AGENT);
      __hip_atomic_store(gen, g + 1, __ATOMIC_RELEASE, __HIP_MEMORY_SCOPE_AGENT);
    } else {
      while (__hip_atomic_load(gen, __ATOMIC_ACQUIRE, __HIP_MEMORY_SCOPE_AGENT) == g)
        __builtin_amdgcn_s_sleep(2);
    }
    __threadfence();
  }
  __syncthreads();
}

// ---- device stage bodies ----
__device__ __forceinline__ void dev_ln(const float* in, const float* w, const float* b,
    float* out, int row, int lane){
  const float4* x4 = (const float4*)(in + (size_t)row * DMODEL);
  float4 v0 = x4[lane], v1 = x4[64 + lane], v2 = x4[128 + lane];
  float s = v0.x+v0.y+v0.z+v0.w + v1.x+v1.y+v1.z+v1.w + v2.x+v2.y+v2.z+v2.w;
  float q = dot4f(v0,v0) + dot4f(v1,v1) + dot4f(v2,v2);
  s = wsum64(s); q = wsum64(q);
  float m = s * (1.0f/DMODEL);
  float r = rsqrtf(q * (1.0f/DMODEL) - m*m + 1e-5f);
  const float4* w4 = (const float4*)w; const float4* b4 = (const float4*)b;
  float4* o4 = (float4*)(out + (size_t)row * DMODEL);
  float4 vv[3] = {v0, v1, v2};
  #pragma unroll
  for (int seg = 0; seg < 3; ++seg){
    float4 ww = w4[seg*64 + lane], bb = b4[seg*64 + lane], x = vv[seg], o;
    o.x = (x.x-m)*r*ww.x + bb.x; o.y = (x.y-m)*r*ww.y + bb.y;
    o.z = (x.z-m)*r*ww.z + bb.z; o.w = (x.w-m)*r*ww.w + bb.w;
    o4[seg*64 + lane] = o;
  }
}

__device__ __forceinline__ void dev_ln2(const float* in,
    const float* w1, const float* b1, const float* w2, const float* b2,
    float* out, int row, int lane){
  const float4* x4 = (const float4*)(in + (size_t)row * DMODEL);
  float4 vv[3] = {x4[lane], x4[64 + lane], x4[128 + lane]};
  float s = 0, q = 0;
  #pragma unroll
  for (int g = 0; g < 3; ++g){ s += vv[g].x+vv[g].y+vv[g].z+vv[g].w; q += dot4f(vv[g], vv[g]); }
  s = wsum64(s); q = wsum64(q);
  float m = s * (1.0f/DMODEL);
  float r = rsqrtf(q * (1.0f/DMODEL) - m*m + 1e-5f);
  const float4* w14 = (const float4*)w1; const float4* b14 = (const float4*)b1;
  float4 yy[3]; float s2 = 0, q2 = 0;
  #pragma unroll
  for (int g = 0; g < 3; ++g){
    float4 ww = w14[g*64 + lane], bb = b14[g*64 + lane], x = vv[g], o;
    o.x = (x.x-m)*r*ww.x + bb.x; o.y = (x.y-m)*r*ww.y + bb.y;
    o.z = (x.z-m)*r*ww.z + bb.z; o.w = (x.w-m)*r*ww.w + bb.w;
    yy[g] = o; s2 += o.x+o.y+o.z+o.w; q2 += dot4f(o,o);
  }
  s2 = wsum64(s2); q2 = wsum64(q2);
  float m2 = s2 * (1.0f/DMODEL);
  float r2 = rsqrtf(q2 * (1.0f/DMODEL) - m2*m2 + 1e-5f);
  const float4* w24 = (const float4*)w2; const float4* b24 = (const float4*)b2;
  float4* o4 = (float4*)(out + (size_t)row * DMODEL);
  #pragma unroll
  for (int g = 0; g < 3; ++g){
    float4 ww = w24[g*64 + lane], bb = b24[g*64 + lane], y = yy[g], o;
    o.x = (y.x-m2)*r2*ww.x + bb.x; o.y = (y.y-m2)*r2*ww.y + bb.y;
    o.z = (y.z-m2)*r2*ww.z + bb.z; o.w = (y.w-m2)*r2*ww.w + bb.w;
    o4[g*64 + lane] = o;
  }
}

// 768x768 GEMM task: task = (bg, jq); ACT: 0 none, 2 acc/3+bias
template<int ACT>
__device__ __forceinline__ void dev_gemm768(const float* A, const float* W,
    const float* bias, float* out, int task, int lane){
  int sl = lane & 7, g = lane >> 3;
  int bg = task & 7; int j0 = (task >> 3) * 4;
  const float4* a4 = (const float4*)(A + (size_t)(bg*8 + g) * DMODEL);
  const float4* w0 = (const float4*)(W + (size_t)(j0+0) * DMODEL);
  const float4* w1 = (const float4*)(W + (size_t)(j0+1) * DMODEL);
  const float4* w2 = (const float4*)(W + (size_t)(j0+2) * DMODEL);
  const float4* w3 = (const float4*)(W + (size_t)(j0+3) * DMODEL);
  float acc0 = 0, acc1 = 0, acc2 = 0, acc3 = 0;
  #pragma unroll 4
  for (int i = 0; i < 24; ++i){
    float4 av = a4[i*8 + sl];
    acc0 += dot4f(av, w0[i*8 + sl]); acc1 += dot4f(av, w1[i*8 + sl]);
    acc2 += dot4f(av, w2[i*8 + sl]); acc3 += dot4f(av, w3[i*8 + sl]);
  }
  #pragma unroll
  for (int o = 1; o <= 4; o <<= 1){
    acc0 += __shfl_xor(acc0, o, 64); acc1 += __shfl_xor(acc1, o, 64);
    acc2 += __shfl_xor(acc2, o, 64); acc3 += __shfl_xor(acc3, o, 64);
  }
  if (sl == 0){
    float4 bj = *(const float4*)(bias + j0);
    float a[4] = {acc0, acc1, acc2, acc3};
    float bb[4] = {bj.x, bj.y, bj.z, bj.w};
    float v[4];
    #pragma unroll
    for (int u = 0; u < 4; ++u)
      v[u] = (ACT == 2) ? a[u]*(1.0f/3.0f) + bb[u] : a[u] + bb[u];
    *(float4*)(out + (size_t)(bg*8 + g) * DMODEL + j0) = make_float4(v[0],v[1],v[2],v[3]);
  }
}

// K=768 -> NC=3072, silu, batch-group loop inside (W read once)
__device__ __forceinline__ void dev_ffn1(const float* A, const float* W,
    const float* bias, float* out, int jq, int lane){
  int sl = lane & 7, g = lane >> 3;
  int j0 = jq * 4;
  const float4* w0 = (const float4*)(W + (size_t)(j0+0) * DMODEL);
  const float4* w1 = (const float4*)(W + (size_t)(j0+1) * DMODEL);
  const float4* w2 = (const float4*)(W + (size_t)(j0+2) * DMODEL);
  const float4* w3 = (const float4*)(W + (size_t)(j0+3) * DMODEL);
  float acc[8][4];
  #pragma unroll
  for (int bg = 0; bg < 8; ++bg)
    #pragma unroll
    for (int u = 0; u < 4; ++u) acc[bg][u] = 0.0f;
  for (int i = 0; i < 24; ++i){
    float4 wv0 = w0[i*8 + sl], wv1 = w1[i*8 + sl], wv2 = w2[i*8 + sl], wv3 = w3[i*8 + sl];
    #pragma unroll
    for (int bg = 0; bg < 8; ++bg){
      float4 av = ((const float4*)(A + (size_t)(bg*8 + g) * DMODEL))[i*8 + sl];
      acc[bg][0] += dot4f(av, wv0); acc[bg][1] += dot4f(av, wv1);
      acc[bg][2] += dot4f(av, wv2); acc[bg][3] += dot4f(av, wv3);
    }
  }
  float4 bj = *(const float4*)(bias + j0);
  float bb[4] = {bj.x, bj.y, bj.z, bj.w};
  #pragma unroll
  for (int bg = 0; bg < 8; ++bg){
    #pragma unroll
    for (int o = 1; o <= 4; o <<= 1)
      #pragma unroll
      for (int u = 0; u < 4; ++u) acc[bg][u] += __shfl_xor(acc[bg][u], o, 64);
    if (sl == 0){
      float v[4];
      #pragma unroll
      for (int u = 0; u < 4; ++u){
        float t = acc[bg][u] + bb[u];
        v[u] = t / (1.0f + __expf(-t));
      }
      *(float4*)(out + (size_t)(bg*8 + g) * FFNH + j0) = make_float4(v[0],v[1],v[2],v[3]);
    }
  }
}

// K=3072 -> NC=768, + bias + residual; task = (jq, bg-pair): 768 tasks
__device__ __forceinline__ void dev_ffn2(const float* A, const float* W,
    const float* bias, const float* res, float* out, int task, int lane){
  int sl = lane & 7, g = lane >> 3;
  int jq = task >> 2, bg0 = (task & 3) * 2;
  int j0 = jq * 4;
  const float4* w0 = (const float4*)(W + (size_t)(j0+0) * FFNH);
  const float4* w1 = (const float4*)(W + (size_t)(j0+1) * FFNH);
  const float4* w2 = (const float4*)(W + (size_t)(j0+2) * FFNH);
  const float4* w3 = (const float4*)(W + (size_t)(j0+3) * FFNH);
  const float4* a0 = (const float4*)(A + (size_t)(bg0*8 + g) * FFNH);
  const float4* a1 = (const float4*)(A + (size_t)((bg0+1)*8 + g) * FFNH);
  float acc[2][4];
  #pragma unroll
  for (int u2 = 0; u2 < 2; ++u2)
    #pragma unroll
    for (int u = 0; u < 4; ++u) acc[u2][u] = 0.0f;
  for (int i = 0; i < 96; ++i){
    float4 wv0 = w0[i*8 + sl], wv1 = w1[i*8 + sl], wv2 = w2[i*8 + sl], wv3 = w3[i*8 + sl];
    float4 av0 = a0[i*8 + sl], av1 = a1[i*8 + sl];
    acc[0][0] += dot4f(av0, wv0); acc[0][1] += dot4f(av0, wv1);
    acc[0][2] += dot4f(av0, wv2); acc[0][3] += dot4f(av0, wv3);
    acc[1][0] += dot4f(av1, wv0); acc[1][1] += dot4f(av1, wv1);
    acc[1][2] += dot4f(av1, wv2); acc[1][3] += dot4f(av1, wv3);
  }
  float4 bj = *(const float4*)(bias + j0);
  float bb[4] = {bj.x, bj.y, bj.z, bj.w};
  #pragma unroll
  for (int u2 = 0; u2 < 2; ++u2){
    #pragma unroll
    for (int o = 1; o <= 4; o <<= 1)
      #pragma unroll
      for (int u = 0; u < 4; ++u) acc[u2][u] += __shfl_xor(acc[u2][u], o, 64);
    if (sl == 0){
      size_t ro = (size_t)((bg0+u2)*8 + g) * DMODEL + j0;
      float4 rr = *(const float4*)(res + ro);
      *(float4*)(out + ro) = make_float4(acc[u2][0]+bb[0]+rr.x, acc[u2][1]+bb[1]+rr.y,
                                         acc[u2][2]+bb[2]+rr.z, acc[u2][3]+bb[3]+rr.w);
    }
  }
}

__device__ __forceinline__ void dev_qpr(const float* qh, const float* Wk,
    const float* snw, const float* snb, const float* bk,
    uint32_t* QWbf, float* SQW, float* SC, int w, int lane){
  int b = w >> 4, h = w & 15;
  uint32_t* qwout = QWbf + (size_t)w * 384;
  if (h >= 12){
    #pragma unroll
    for (int k = 0; k < 6; ++k) qwout[k*64 + lane] = 0;
    if (lane == 0){ SQW[w] = 0.0f; SC[w] = 0.0f; }
    return;
  }
  const float* qrow = qh + (size_t)b * DMODEL + h * DHEAD;
  const float* wbase = Wk + (size_t)h * DHEAD * DMODEL;
  float qa[6] = {0,0,0,0,0,0}, qb[6] = {0,0,0,0,0,0};
  for (int e = 0; e < DHEAD; ++e){
    float qv = qrow[e];
    const float* wr = wbase + (size_t)e * DMODEL + 2*lane;
    #pragma unroll
    for (int k = 0; k < 6; ++k){
      qa[k] = fmaf(qv, wr[k*128], qa[k]);
      qb[k] = fmaf(qv, wr[k*128 + 1], qb[k]);
    }
  }
  float s1 = 0, s2 = 0;
  #pragma unroll
  for (int k = 0; k < 6; ++k){
    int d0 = k*128 + 2*lane;
    float va = qa[k] * snw[d0]   * 0.125f;
    float vb = qb[k] * snw[d0+1] * 0.125f;
    uint32_t pr = bfpair(va, vb);
    qwout[k*64 + lane] = pr;
    s1 += __uint_as_float(pr << 16) + __uint_as_float(pr & 0xFFFF0000u);
    s2 = fmaf(qa[k], snb[d0], fmaf(qb[k], snb[d0+1], s2));
  }
  float s3 = qrow[lane] * bk[h*DHEAD + lane];
  s1 = wsum64(s1); s2 = wsum64(s2); s3 = wsum64(s3);
  if (lane == 0){ SQW[w] = s1; SC[w] = 0.125f * (s2 + s3); }
}

__device__ __forceinline__ void dev_comb(int t, const float* Pacc, const float* Pden,
    const float* Pc, const float* Pmx, const int* lens,
    const float* snw, const float* snb, float* wsum){
  int d = t % DMODEL;
  int u = t / DMODEL;
  int h = u % NHEAD;
  int b = u / NHEAD;
  float vec = 0.0f, csum = 0.0f;
  #pragma unroll
  for (int n = 0; n < NDOM; ++n){
    int nb = n*NB + b;
    int len = lens[nb];
    int na = (len + ROWCH - 1) >> 6; if (na > NCH) na = NCH;
    size_t p0 = (size_t)(nb * NCH) * NHEAD + h;
    float M = -3.0e38f;
    for (int c = 0; c < na; ++c) M = fmaxf(M, Pmx[p0 + (size_t)c*NHEAD]);
    float D = 0, V = 0, C = 0;
    for (int c = 0; c < na; ++c){
      size_t pi = p0 + (size_t)c*NHEAD;
      float w = __expf(Pmx[pi] - M);
      D = fmaf(w, Pden[pi], D);
      V = fmaf(w, Pacc[pi*DMODEL + d], V);
      C = fmaf(w, Pc[pi], C);
    }
    float inv = 1.0f / D;
    vec = fmaf(V, inv, vec);
    csum = fmaf(C, inv, csum);
  }
  wsum[t] = (vec - csum) * snw[d] + 3.0f * snb[d];
}

__device__ __forceinline__ void dev_ctxv(const float* wsum, const float* Wv,
    const float* bv, float* ctxsum, int task, int lane){
  int sl = lane & 7, g = lane >> 3;
  int bg = task & 7; int j0 = (task >> 3) * 4;
  int h = j0 >> 6;
  const float4* a4 = (const float4*)(wsum + ((size_t)(bg*8 + g) * NHEAD + h) * DMODEL);
  const float4* w0 = (const float4*)(Wv + (size_t)(j0+0) * DMODEL);
  const float4* w1 = (const float4*)(Wv + (size_t)(j0+1) * DMODEL);
  const float4* w2 = (const float4*)(Wv + (size_t)(j0+2) * DMODEL);
  const float4* w3 = (const float4*)(Wv + (size_t)(j0+3) * DMODEL);
  float acc0 = 0, acc1 = 0, acc2 = 0, acc3 = 0;
  #pragma unroll 4
  for (int i = 0; i < 24; ++i){
    float4 av = a4[i*8 + sl];
    acc0 += dot4f(av, w0[i*8 + sl]); acc1 += dot4f(av, w1[i*8 + sl]);
    acc2 += dot4f(av, w2[i*8 + sl]); acc3 += dot4f(av, w3[i*8 + sl]);
  }
  #pragma unroll
  for (int o = 1; o <= 4; o <<= 1){
    acc0 += __shfl_xor(acc0, o, 64); acc1 += __shfl_xor(acc1, o, 64);
    acc2 += __shfl_xor(acc2, o, 64); acc3 += __shfl_xor(acc3, o, 64);
  }
  if (sl == 0){
    float4 bb = *(const float4*)(bv + j0);
    *(float4*)(ctxsum + (size_t)(bg*8 + g) * DMODEL + j0) =
      make_float4(acc0 + 3.0f*bb.x, acc1 + 3.0f*bb.y, acc2 + 3.0f*bb.z, acc3 + 3.0f*bb.w);
  }
}

__device__ __forceinline__ void dev_gate(const float* ctx, const float* sctx,
    const float* Wg, const float* gb, float* out, int task, int lane){
  int sl = lane & 7, g = lane >> 3;
  int bg = task & 7; int j0 = (task >> 3) * 4;
  int row = bg*8 + g;
  const float4* c4 = (const float4*)(ctx + (size_t)row * DMODEL);
  const float4* s4 = (const float4*)(sctx + (size_t)row * DMODEL);
  const float4* wr0 = (const float4*)(Wg + (size_t)(j0+0) * 2 * DMODEL);
  const float4* wr1 = (const float4*)(Wg + (size_t)(j0+1) * 2 * DMODEL);
  const float4* wr2 = (const float4*)(Wg + (size_t)(j0+2) * 2 * DMODEL);
  const float4* wr3 = (const float4*)(Wg + (size_t)(j0+3) * 2 * DMODEL);
  float acc0 = 0, acc1 = 0, acc2 = 0, acc3 = 0;
  #pragma unroll 4
  for (int i = 0; i < 24; ++i){
    float4 cv = c4[i*8 + sl], sv = s4[i*8 + sl];
    acc0 += dot4f(cv, wr0[i*8 + sl]) + dot4f(sv, wr0[192 + i*8 + sl]);
    acc1 += dot4f(cv, wr1[i*8 + sl]) + dot4f(sv, wr1[192 + i*8 + sl]);
    acc2 += dot4f(cv, wr2[i*8 + sl]) + dot4f(sv, wr2[192 + i*8 + sl]);
    acc3 += dot4f(cv, wr3[i*8 + sl]) + dot4f(sv, wr3[192 + i*8 + sl]);
  }
  #pragma unroll
  for (int o = 1; o <= 4; o <<= 1){
    acc0 += __shfl_xor(acc0, o, 64); acc1 += __shfl_xor(acc1, o, 64);
    acc2 += __shfl_xor(acc2, o, 64); acc3 += __shfl_xor(acc3, o, 64);
  }
  if (sl == 0){
    size_t o = (size_t)row * DMODEL + j0;
    float4 bb = *(const float4*)(gb + j0);
    float4 cc = *(const float4*)(ctx + o);
    float4 ss = *(const float4*)(sctx + o);
    float4 v;
    v.x = cc.x + ss.x / (1.0f + __expf(-(acc0 + bb.x)));
    v.y = cc.y + ss.y / (1.0f + __expf(-(acc1 + bb.y)));
    v.z = cc.z + ss.z / (1.0f + __expf(-(acc2 + bb.z)));
    v.w = cc.w + ss.w / (1.0f + __expf(-(acc3 + bb.w)));
    *(float4*)(out + o) = v;
  }
}

// -------- prep (once): LN stats + bf16 copy, len-gated --------
__global__ __launch_bounds__(256) void k_prep(const float* __restrict__ seq,
    const int* __restrict__ lens, uint32_t* __restrict__ xbf,
    float* __restrict__ mstat, float* __restrict__ rstat){
  int gw = (blockIdx.x * 256 + threadIdx.x) >> 6;
  int lane = threadIdx.x & 63;
  int nb = gw >> 9, s = gw & 511;
  if (s >= lens[nb]) return;
  const float4* x4 = (const float4*)(seq + (size_t)gw * DMODEL);
  float4 v0 = x4[lane], v1 = x4[64 + lane], v2 = x4[128 + lane];
  float sm = v0.x+v0.y+v0.z+v0.w + v1.x+v1.y+v1.z+v1.w + v2.x+v2.y+v2.z+v2.w;
  float q = dot4f(v0,v0) + dot4f(v1,v1) + dot4f(v2,v2);
  sm = wsum64(sm); q = wsum64(q);
  float m = sm * (1.0f/DMODEL);
  float r = rsqrtf(q * (1.0f/DMODEL) - m*m + 1e-5f);
  if (lane == 0){ mstat[gw] = m; rstat[gw] = r; }
  uint32_t* o = xbf + (size_t)gw * 384;
  o[2*lane]       = bfpair(v0.x, v0.y);
  o[2*lane+1]     = bfpair(v0.z, v0.w);
  o[128+2*lane]   = bfpair(v1.x, v1.y);
  o[128+2*lane+1] = bfpair(v1.z, v1.w);
  o[256+2*lane]   = bfpair(v2.x, v2.y);
  o[256+2*lane+1] = bfpair(v2.z, v2.w);
}

// -------- persistent per-layer mega-kernel --------
__global__ __launch_bounds__(1024) void k_layer(
    int* bcnt, int* bgen, int last,
    const float* cur, float* nxt, const int* lens,
    const uint32_t* xbf, const float* mstat, const float* rstat,
    const float* qn_w, const float* qn_b, const float* sn_w, const float* sn_b,
    const float* Wq, const float* bq, const float* Wk, const float* bk,
    const float* Wv, const float* bv,
    const float* out_w, const float* out_b,
    const float* gate_w, const float* gate_b,
    const float* fln_w, const float* fln_b,
    const float* fw1, const float* fb1, const float* fw2, const float* fb2,
    float* qln, float* qh, uint32_t* QWbf, float* SQW, float* SC,
    float* Pacc, float* Pden, float* Pc, float* Pmx,
    float* wsumb, float* ctxsum, float* sctx, float* cmid, float* h0, float* h1,
    const float* on_w, const float* on_b, const float* cl_w, const float* cl_b,
    const float* cw1, const float* cb1, const float* cw2, const float* cb2,
    float* outp){
  __shared__ float er_lds[4][64*17];
  __shared__ float tmax[4][4][16], tsum[4][4][16], tcs[4][4][16], fls[4][4][16];
  const int tid = threadIdx.x;
  const int gw = blockIdx.x * 16 + (tid >> 6);
  const int lane = tid & 63;

  // S1: qln = LN(cur)
  if (gw < 64) dev_ln(cur, qn_w, qn_b, qln, gw, lane);
  gbar(bcnt, bgen);
  // S2: qh = qln @ Wq^T + bq
  if (gw < 1536) dev_gemm768<0>(qln, Wq, bq, qh, gw, lane);
  gbar(bcnt, bgen);
  // S3: qpr
  if (gw < 1024) dev_qpr(qh, Wk, sn_w, sn_b, bk, QWbf, SQW, SC, gw, lane);
  gbar(bcnt, bgen);

  // S4: attention (uniform barriers; 1536 group-tasks over 1024 groups, 2 iters)
  {
    int gl = tid >> 8, gtid = tid & 255, wid = gtid >> 6;
    int l15 = lane & 15, mg = lane >> 4;
    for (int it = 0; it < 2; ++it){
      __syncthreads();
      int task = blockIdx.x * 4 + gl + it * 1024;
      bool act = false; int nb = 0, len = 0, s0 = 0, b = 0;
      if (task < 1536){
        nb = task >> 3; int ch = task & 7;
        len = lens[nb]; s0 = ch * 64; b = nb % NB;
        act = (s0 < len);
      }
      int r0 = s0 + wid * 16;
      float tm = -3.0e38f, es = 0.0f, cs = 0.0f;
      if (act){
        const short8* ax = (const short8*)(xbf + ((size_t)(nb*SEQLEN + r0 + l15)) * 384) + mg;
        const short8* bq8 = (const short8*)(QWbf + ((size_t)(b*16 + l15)) * 384) + mg;
        f32x4 acc = {0.0f, 0.0f, 0.0f, 0.0f};
        #pragma unroll
        for (int kk = 0; kk < 24; ++kk)
          acc = __builtin_amdgcn_mfma_f32_16x16x32_bf16(ax[kk*4], bq8[kk*4], acc, 0, 0, 0);
        float sqw = SQW[b*16 + l15], scc = SC[b*16 + l15];
        float sco[4];
        #pragma unroll
        for (int j = 0; j < 4; ++j){
          int s = r0 + mg*4 + j;
          float mm = mstat[(size_t)nb*SEQLEN + s];
          float v = rstat[(size_t)nb*SEQLEN + s] * (acc[j] - mm * sqw) + scc;
          sco[j] = (s < len) ? v : -3.0e38f;
        }
        tm = fmaxf(fmaxf(sco[0], sco[1]), fmaxf(sco[2], sco[3]));
        tm = fmaxf(tm, __shfl_xor(tm, 16, 64));
        tm = fmaxf(tm, __shfl_xor(tm, 32, 64));
        #pragma unroll
        for (int j = 0; j < 4; ++j){
          int s = r0 + mg*4 + j;
          float e = (sco[j] > -1.0e37f) ? __expf(sco[j] - tm) : 0.0f;
          float rr = rstat[(size_t)nb*SEQLEN + s];
          float er = e * rr;
          er_lds[gl][(wid*16 + mg*4 + j)*17 + l15] = er;
          es += e;
          cs = fmaf(er, mstat[(size_t)nb*SEQLEN + s], cs);
        }
        es += __shfl_xor(es, 16, 64); es += __shfl_xor(es, 32, 64);
        cs += __shfl_xor(cs, 16, 64); cs += __shfl_xor(cs, 32, 64);
      }
      if (lane < 16){
        tmax[gl][wid][lane] = act ? tm : -3.0e38f;
        tsum[gl][wid][lane] = act ? es : 0.0f;
        tcs[gl][wid][lane]  = act ? cs : 0.0f;
      }
      __syncthreads();
      if (gtid < 16){
        int hh = gtid;
        float M = fmaxf(fmaxf(tmax[gl][0][hh], tmax[gl][1][hh]),
                        fmaxf(tmax[gl][2][hh], tmax[gl][3][hh]));
        float D = 0, C = 0;
        #pragma unroll
        for (int w = 0; w < 4; ++w){
          float f = (tmax[gl][w][hh] > -1.0e37f) ? __expf(tmax[gl][w][hh] - M) : 0.0f;
          fls[gl][w][hh] = f;
          D = fmaf(f, tsum[gl][w][hh], D);
          C = fmaf(f, tcs[gl][w][hh], C);
        }
        if (act && hh < NHEAD){
          Pmx[(size_t)task*NHEAD + hh] = M;
          Pden[(size_t)task*NHEAD + hh] = D;
          Pc[(size_t)task*NHEAD + hh] = C;
        }
      }
      __syncthreads();
      #pragma unroll
      for (int t2 = 0; t2 < 4; ++t2){
        int i = gtid + t2*256;
        int row = i >> 4, hh = i & 15;
        er_lds[gl][row*17 + hh] *= fls[gl][row >> 4][hh];
      }
      __syncthreads();
      if (act){
        int h0w = wid * 3;
        float a[3][12];
        #pragma unroll
        for (int j = 0; j < 3; ++j)
          #pragma unroll
          for (int c = 0; c < 12; ++c) a[j][c] = 0.0f;
        const uint32_t* xr0 = xbf + ((size_t)(nb*SEQLEN + s0)) * 384 + lane*6;
        int nrows = len - s0; if (nrows > ROWCH) nrows = ROWCH;
        for (int s = 0; s < nrows; ++s){
          const uint32_t* xr = xr0 + (size_t)s * 384;
          uint2 u01 = *(const uint2*)(xr);
          uint2 u23 = *(const uint2*)(xr + 2);
          uint2 u45 = *(const uint2*)(xr + 4);
          float e0 = er_lds[gl][s*17 + h0w], e1 = er_lds[gl][s*17 + h0w + 1], e2 = er_lds[gl][s*17 + h0w + 2];
          float x[12];
          x[0]  = __uint_as_float(u01.x << 16); x[1]  = __uint_as_float(u01.x & 0xFFFF0000u);
          x[2]  = __uint_as_float(u01.y << 16); x[3]  = __uint_as_float(u01.y & 0xFFFF0000u);
          x[4]  = __uint_as_float(u23.x << 16); x[5]  = __uint_as_float(u23.x & 0xFFFF0000u);
          x[6]  = __uint_as_float(u23.y << 16); x[7]  = __uint_as_float(u23.y & 0xFFFF0000u);
          x[8]  = __uint_as_float(u45.x << 16); x[9]  = __uint_as_float(u45.x & 0xFFFF0000u);
          x[10] = __uint_as_float(u45.y << 16); x[11] = __uint_as_float(u45.y & 0xFFFF0000u);
          #pragma unroll
          for (int c = 0; c < 12; ++c){
            a[0][c] = fmaf(e0, x[c], a[0][c]);
            a[1][c] = fmaf(e1, x[c], a[1][c]);
            a[2][c] = fmaf(e2, x[c], a[2][c]);
          }
        }
        #pragma unroll
        for (int j = 0; j < 3; ++j){
          float* p = Pacc + ((size_t)task*NHEAD + h0w + j) * DMODEL + lane*12;
          #pragma unroll
          for (int c = 0; c < 12; c += 4)
            *(float4*)(p + c) = make_float4(a[j][c], a[j][c+1], a[j][c+2], a[j][c+3]);
        }
      }
    }
  }
  gbar(bcnt, bgen);

  // S5: combine
  for (int t = blockIdx.x * 1024 + tid; t < NB*NHEAD*DMODEL; t += NBLOCKS*NTHREADS)
    dev_comb(t, Pacc, Pden, Pc, Pmx, lens, sn_w, sn_b, wsumb);
  gbar(bcnt, bgen);
  // S6: ctxsum
  if (gw < 1536) dev_ctxv(wsumb, Wv, bv, ctxsum, gw, lane);
  gbar(bcnt, bgen);
  // S7: sctx = ctxsum @ out_w^T /3 + out_b
  if (gw < 1536) dev_gemm768<2>(ctxsum, out_w, out_b, sctx, gw, lane);
  gbar(bcnt, bgen);
  // S8: gate -> cmid
  if (gw < 1536) dev_gate(cur, sctx, gate_w, gate_b, cmid, gw, lane);
  gbar(bcnt, bgen);
  // S9: h0 = LN(cmid)
  if (gw < 64) dev_ln(cmid, fln_w, fln_b, h0, gw, lane);
  gbar(bcnt, bgen);
  // S10: h1 = silu(h0 @ fw1^T + fb1)
  if (gw < 768) dev_ffn1(h0, fw1, fb1, h1, gw, lane);
  gbar(bcnt, bgen);
  // S11: nxt = h1 @ fw2^T + fb2 + cmid
  if (gw < 768) dev_ffn2(h1, fw2, fb2, cmid, nxt, gw, lane);

  if (last){
    gbar(bcnt, bgen);
    // F1: h0 = LN2(nxt)
    if (gw < 64) dev_ln2(nxt, on_w, on_b, cl_w, cl_b, h0, gw, lane);
    gbar(bcnt, bgen);
    // F2: h1 = silu(h0 @ cw1^T + cb1)
    if (gw < 768) dev_ffn1(h0, cw1, cb1, h1, gw, lane);
    gbar(bcnt, bgen);
    // F3: out[b]
    if (gw < 64){
      float acc = 0;
      for (int k = 0; k < 48; ++k){
        int j = lane + k*64;
        acc = fmaf(h1[(size_t)gw*FFNH + j], cw2[j], acc);
      }
      acc = wsum64(acc);
      if (lane == 0) outp[gw] = acc + cb2[0];
    }
  }
}

extern "C" void kernel_launch(void* const* d_in, const int* in_sizes, int n_in,
                              void* d_out, int out_size, void* d_ws, size_t ws_size,
                              hipStream_t stream){
  const float* in_ctx = (const float*)d_in[0];
  const float* seq    = (const float*)d_in[1];
  const int*   lens   = (const int*)d_in[2];
  const float* qn_w   = (const float*)d_in[3];
  const float* qn_b   = (const float*)d_in[4];
  const float* sn_w   = (const float*)d_in[5];
  const float* sn_b   = (const float*)d_in[6];
  const float* in_w   = (const float*)d_in[7];
  const float* in_b   = (const float*)d_in[8];
  const float* out_w  = (const float*)d_in[9];
  const float* out_b  = (const float*)d_in[10];
  const float* gate_w = (const float*)d_in[11];
  const float* gate_b = (const float*)d_in[12];
  const float* fln_w  = (const float*)d_in[13];
  const float* fln_b  = (const float*)d_in[14];
  const float* fw1    = (const float*)d_in[15];
  const float* fb1    = (const float*)d_in[16];
  const float* fw2    = (const float*)d_in[17];
  const float* fb2    = (const float*)d_in[18];
  const float* on_w   = (const float*)d_in[19];
  const float* on_b   = (const float*)d_in[20];
  const float* cl_w   = (const float*)d_in[21];
  const float* cl_b   = (const float*)d_in[22];
  const float* cw1    = (const float*)d_in[23];
  const float* cb1    = (const float*)d_in[24];
  const float* cw2    = (const float*)d_in[25];
  const float* cb2    = (const float*)d_in[26];

  float* wsf = (float*)d_ws;
  size_t off = 0;
  auto alloc = [&](size_t n){ float* p = wsf + off; off += n; return p; };
  int*   bar    = (int*)alloc(4);
  float* c0     = alloc((size_t)NB*DMODEL);
  float* c1     = alloc((size_t)NB*DMODEL);
  float* cmid   = alloc((size_t)NB*DMODEL);
  float* qln    = alloc((size_t)NB*DMODEL);
  float* qh     = alloc((size_t)NB*DMODEL);
  uint32_t* QWbf = (uint32_t*)alloc((size_t)NB*16*384);
  float* SQWb   = alloc((size_t)NB*16);
  float* SCb    = alloc((size_t)NB*16);
  uint32_t* xbf = (uint32_t*)alloc((size_t)NBROWS*SEQLEN*384);
  float* mstat  = alloc((size_t)NBROWS*SEQLEN);
  float* rstat  = alloc((size_t)NBROWS*SEQLEN);
  float* Pacc   = alloc((size_t)NBROWS*NCH*NHEAD*DMODEL);
  float* Pden   = alloc((size_t)NBROWS*NCH*NHEAD);
  float* Pc     = alloc((size_t)NBROWS*NCH*NHEAD);
  float* Pmx    = alloc((size_t)NBROWS*NCH*NHEAD);
  float* wsumb  = alloc((size_t)NB*NHEAD*DMODEL);
  float* ctxsum = alloc((size_t)NB*DMODEL);
  float* sctx   = alloc((size_t)NB*DMODEL);
  float* h0     = alloc((size_t)NB*DMODEL);
  float* h1     = alloc((size_t)NB*FFNH);
  (void)ws_size; (void)in_sizes; (void)n_in; (void)out_size;

  hipMemsetAsync(bar, 0, 16, stream);
  hipMemcpyAsync(c0, in_ctx, (size_t)NB*DMODEL*sizeof(float), hipMemcpyDeviceToDevice, stream);
  k_prep<<<(NBROWS*SEQLEN)/4, 256, 0, stream>>>(seq, lens, xbf, mstat, rstat);

  float* cur = c0; float* nxt = c1;
  for (int l = 0; l < NBLK; ++l){
    const float* Wq = in_w + (size_t)l * 3 * DMODEL * DMODEL;
    const float* Wk = Wq + (size_t)DMODEL * DMODEL;
    const float* Wv = Wq + (size_t)2 * DMODEL * DMODEL;
    const float* bq = in_b + (size_t)l * 3 * DMODEL;
    const float* bk = bq + DMODEL;
    const float* bv = bq + 2 * DMODEL;
    k_layer<<<NBLOCKS, NTHREADS, 0, stream>>>(
      bar, bar + 1, (l == NBLK-1) ? 1 : 0,
      cur, nxt, lens, xbf, mstat, rstat,
      qn_w + l*DMODEL, qn_b + l*DMODEL, sn_w + l*DMODEL, sn_b + l*DMODEL,
      Wq, bq, Wk, bk, Wv, bv,
      out_w + (size_t)l*DMODEL*DMODEL, out_b + l*DMODEL,
      gate_w + (size_t)l*DMODEL*2*DMODEL, gate_b + l*DMODEL,
      fln_w + l*DMODEL, fln_b + l*DMODEL,
      fw1 + (size_t)l*FFNH*DMODEL, fb1 + l*FFNH,
      fw2 + (size_t)l*DMODEL*FFNH, fb2 + l*DMODEL,
      qln, qh, QWbf, SQWb, SCb, Pacc, Pden, Pc, Pmx,
      wsumb, ctxsum, sctx, cmid, h0, h1,
      on_w, on_b, cl_w, cl_b, cw1, cb1, cw2, cb2, (float*)d_out);
    float* t = cur; cur = nxt; nxt = t;
  }
}

// Round 10
// 547.100 us; speedup vs baseline: 7.8194x; 7.8194x over previous
//
#include <hip/hip_runtime.h>
#include <hip/hip_bf16.h>
#include <cstdint>

#define DMODEL 768
#define NB 64
#define NHEAD 12
#define DHEAD 64
#define SEQLEN 512
#define NDOM 3
#define NBLK 2
#define FFNH 3072
#define NBROWS (NDOM*NB)   // 192
#define NCH 8              // 64-row chunks
#define ROWCH 64

typedef __attribute__((ext_vector_type(8))) short short8;
typedef __attribute__((ext_vector_type(4))) float f32x4;

__device__ __forceinline__ float wsum64(float v){
  #pragma unroll
  for (int o = 32; o; o >>= 1) v += __shfl_xor(v, o, 64);
  return v;
}
__device__ __forceinline__ float dot4f(float4 a, float4 b){
  return fmaf(a.x, b.x, fmaf(a.y, b.y, fmaf(a.z, b.z, a.w * b.w)));
}
__device__ __forceinline__ uint32_t bfpair(float lo, float hi){
  uint32_t ul = __float_as_uint(lo), uh = __float_as_uint(hi);
  ul = (ul + 0x7FFFu + ((ul >> 16) & 1u)) >> 16;
  uh = (uh + 0x7FFFu + ((uh >> 16) & 1u)) & 0xFFFF0000u;
  return ul | uh;
}

// -------- LayerNorm: one wave per row --------
__global__ __launch_bounds__(256) void k_ln(const float* __restrict__ in,
    const float* __restrict__ w, const float* __restrict__ b,
    float* __restrict__ out, int rows){
  int gw = (blockIdx.x * 256 + threadIdx.x) >> 6;
  int lane = threadIdx.x & 63;
  if (gw >= rows) return;
  const float4* x4 = (const float4*)(in + (size_t)gw * DMODEL);
  float4 v0 = x4[lane], v1 = x4[64 + lane], v2 = x4[128 + lane];
  float s = v0.x+v0.y+v0.z+v0.w + v1.x+v1.y+v1.z+v1.w + v2.x+v2.y+v2.z+v2.w;
  float q = dot4f(v0,v0) + dot4f(v1,v1) + dot4f(v2,v2);
  s = wsum64(s); q = wsum64(q);
  float m = s * (1.0f / DMODEL);
  float r = rsqrtf(q * (1.0f / DMODEL) - m * m + 1e-5f);
  const float4* w4 = (const float4*)w;
  const float4* b4 = (const float4*)b;
  float4* o4 = (float4*)(out + (size_t)gw * DMODEL);
  float4 vv[3] = {v0, v1, v2};
  #pragma unroll
  for (int seg = 0; seg < 3; ++seg){
    float4 ww = w4[seg*64 + lane], bb = b4[seg*64 + lane], x = vv[seg], o;
    o.x = (x.x - m) * r * ww.x + bb.x;
    o.y = (x.y - m) * r * ww.y + bb.y;
    o.z = (x.z - m) * r * ww.z + bb.z;
    o.w = (x.w - m) * r * ww.w + bb.w;
    o4[seg*64 + lane] = o;
  }
}

// -------- double LayerNorm --------
__global__ __launch_bounds__(256) void k_ln2(const float* __restrict__ in,
    const float* __restrict__ w1, const float* __restrict__ b1,
    const float* __restrict__ w2, const float* __restrict__ b2,
    float* __restrict__ out, int rows){
  int gw = (blockIdx.x * 256 + threadIdx.x) >> 6;
  int lane = threadIdx.x & 63;
  if (gw >= rows) return;
  const float4* x4 = (const float4*)(in + (size_t)gw * DMODEL);
  float4 vv[3] = {x4[lane], x4[64 + lane], x4[128 + lane]};
  float s = 0, q = 0;
  #pragma unroll
  for (int g = 0; g < 3; ++g){ s += vv[g].x+vv[g].y+vv[g].z+vv[g].w; q += dot4f(vv[g], vv[g]); }
  s = wsum64(s); q = wsum64(q);
  float m = s * (1.0f/DMODEL);
  float r = rsqrtf(q * (1.0f/DMODEL) - m*m + 1e-5f);
  const float4* w14 = (const float4*)w1; const float4* b14 = (const float4*)b1;
  float4 yy[3]; float s2 = 0, q2 = 0;
  #pragma unroll
  for (int g = 0; g < 3; ++g){
    float4 ww = w14[g*64 + lane], bb = b14[g*64 + lane], x = vv[g], o;
    o.x = (x.x-m)*r*ww.x + bb.x; o.y = (x.y-m)*r*ww.y + bb.y;
    o.z = (x.z-m)*r*ww.z + bb.z; o.w = (x.w-m)*r*ww.w + bb.w;
    yy[g] = o; s2 += o.x+o.y+o.z+o.w; q2 += dot4f(o,o);
  }
  s2 = wsum64(s2); q2 = wsum64(q2);
  float m2 = s2 * (1.0f/DMODEL);
  float r2 = rsqrtf(q2 * (1.0f/DMODEL) - m2*m2 + 1e-5f);
  const float4* w24 = (const float4*)w2; const float4* b24 = (const float4*)b2;
  float4* o4 = (float4*)(out + (size_t)gw * DMODEL);
  #pragma unroll
  for (int g = 0; g < 3; ++g){
    float4 ww = w24[g*64 + lane], bb = b24[g*64 + lane], y = yy[g], o;
    o.x = (y.x-m2)*r2*ww.x + bb.x; o.y = (y.y-m2)*r2*ww.y + bb.y;
    o.z = (y.z-m2)*r2*ww.z + bb.z; o.w = (y.w-m2)*r2*ww.w + bb.w;
    o4[g*64 + lane] = o;
  }
}

// -------- wave-per-4-columns GEMM --------
template<int K, int NC, int ACT, bool RES>
__global__ __launch_bounds__(256) void k_gemmW(const float* __restrict__ A,
    const float* __restrict__ W, const float* __restrict__ bias,
    const float* __restrict__ res, float* __restrict__ out){
  int gw = (blockIdx.x * 256 + threadIdx.x) >> 6;
  int lane = threadIdx.x & 63;
  int sl = lane & 7, g = lane >> 3;
  int bg = gw & 7; int j0 = (gw >> 3) * 4;
  const float4* a4 = (const float4*)(A + (size_t)(bg*8 + g) * K);
  const float4* w0 = (const float4*)(W + (size_t)(j0+0) * K);
  const float4* w1 = (const float4*)(W + (size_t)(j0+1) * K);
  const float4* w2 = (const float4*)(W + (size_t)(j0+2) * K);
  const float4* w3 = (const float4*)(W + (size_t)(j0+3) * K);
  float acc0 = 0, acc1 = 0, acc2 = 0, acc3 = 0;
  #pragma unroll 4
  for (int i = 0; i < K/32; ++i){
    float4 av = a4[i*8 + sl];
    acc0 += dot4f(av, w0[i*8 + sl]);
    acc1 += dot4f(av, w1[i*8 + sl]);
    acc2 += dot4f(av, w2[i*8 + sl]);
    acc3 += dot4f(av, w3[i*8 + sl]);
  }
  #pragma unroll
  for (int o = 1; o <= 4; o <<= 1){
    acc0 += __shfl_xor(acc0, o, 64);
    acc1 += __shfl_xor(acc1, o, 64);
    acc2 += __shfl_xor(acc2, o, 64);
    acc3 += __shfl_xor(acc3, o, 64);
  }
  if (sl == 0){
    int row = bg*8 + g;
    float4 bj = *(const float4*)(bias + j0);
    float a[4] = {acc0, acc1, acc2, acc3};
    float bb[4] = {bj.x, bj.y, bj.z, bj.w};
    float v[4];
    #pragma unroll
    for (int u = 0; u < 4; ++u){
      float t = (ACT == 2) ? a[u] * (1.0f/3.0f) + bb[u] : a[u] + bb[u];
      if (ACT == 1) t = t / (1.0f + __expf(-t));
      v[u] = t;
    }
    size_t o = (size_t)row * NC + j0;
    if (RES){
      float4 rr = *(const float4*)(res + o);
      v[0] += rr.x; v[1] += rr.y; v[2] += rr.z; v[3] += rr.w;
    }
    *(float4*)(out + o) = make_float4(v[0], v[1], v[2], v[3]);
  }
}

// -------- fused query head: LN(ctx) + Wq proj + qproj/reductions --------
// block = (b, head-quarter qq); qq==3 writes the 4 pad heads (zeros).
// Stage1: LN row b -> qln_lds. Stage2: thread t computes qh col qq*256+t from LDS.
// Stage3: wave wid handles head qq*4+wid using qh_lds (R8 k_qpr body).
__global__ __launch_bounds__(256) void k_qhead(const float* __restrict__ cur,
    const float* __restrict__ qn_w, const float* __restrict__ qn_b,
    const float* __restrict__ Wq, const float* __restrict__ bq,
    const float* __restrict__ Wk, const float* __restrict__ bk,
    const float* __restrict__ snw, const float* __restrict__ snb,
    uint32_t* __restrict__ QWbf, float* __restrict__ SQW, float* __restrict__ SC){
  __shared__ float qln_lds[DMODEL];
  __shared__ float qh_lds[256];
  __shared__ float red[8];
  int blk = blockIdx.x;
  int qq = blk & 3, b = blk >> 2;
  int tid = threadIdx.x, lane = tid & 63, wid = tid >> 6;
  if (qq == 3){
    int w16 = b*16 + 12 + wid;
    uint32_t* qwout = QWbf + (size_t)w16 * 384;
    #pragma unroll
    for (int k = 0; k < 6; ++k) qwout[k*64 + lane] = 0;
    if (lane == 0){ SQW[w16] = 0.0f; SC[w16] = 0.0f; }
    return;
  }
  // stage 1: LN row b
  {
    float x0 = cur[(size_t)b*DMODEL + tid];
    float x1 = cur[(size_t)b*DMODEL + 256 + tid];
    float x2 = cur[(size_t)b*DMODEL + 512 + tid];
    float s = x0 + x1 + x2;
    float q = x0*x0 + x1*x1 + x2*x2;
    s = wsum64(s); q = wsum64(q);
    if (lane == 0){ red[wid] = s; red[4 + wid] = q; }
    __syncthreads();
    float st = red[0] + red[1] + red[2] + red[3];
    float qt = red[4] + red[5] + red[6] + red[7];
    float m = st * (1.0f/DMODEL);
    float r = rsqrtf(qt * (1.0f/DMODEL) - m*m + 1e-5f);
    qln_lds[tid]       = (x0 - m)*r*qn_w[tid]       + qn_b[tid];
    qln_lds[256 + tid] = (x1 - m)*r*qn_w[256 + tid] + qn_b[256 + tid];
    qln_lds[512 + tid] = (x2 - m)*r*qn_w[512 + tid] + qn_b[512 + tid];
  }
  __syncthreads();
  // stage 2: qh col = qq*256 + tid
  {
    int col = qq*256 + tid;
    const float4* wr = (const float4*)(Wq + (size_t)col * DMODEL);
    const float4* ql = (const float4*)qln_lds;
    float acc = 0;
    #pragma unroll 8
    for (int i = 0; i < 192; ++i) acc += dot4f(ql[i], wr[i]);
    qh_lds[tid] = acc + bq[col];
  }
  __syncthreads();
  // stage 3: qpr for head hh = qq*4 + wid
  {
    int hh = qq*4 + wid;
    int w16 = b*16 + hh;
    const float* qrow = qh_lds + wid*64;
    const float* wbase = Wk + (size_t)hh * DHEAD * DMODEL;
    float qa[6] = {0,0,0,0,0,0}, qb[6] = {0,0,0,0,0,0};
    for (int e = 0; e < DHEAD; ++e){
      float qv = qrow[e];
      const float* wr = wbase + (size_t)e * DMODEL + 2*lane;
      #pragma unroll
      for (int k = 0; k < 6; ++k){
        qa[k] = fmaf(qv, wr[k*128], qa[k]);
        qb[k] = fmaf(qv, wr[k*128 + 1], qb[k]);
      }
    }
    uint32_t* qwout = QWbf + (size_t)w16 * 384;
    float s1 = 0, s2 = 0;
    #pragma unroll
    for (int k = 0; k < 6; ++k){
      int d0 = k*128 + 2*lane;
      float va = qa[k] * snw[d0]   * 0.125f;
      float vb = qb[k] * snw[d0+1] * 0.125f;
      uint32_t pr = bfpair(va, vb);
      qwout[k*64 + lane] = pr;
      s1 += __uint_as_float(pr << 16) + __uint_as_float(pr & 0xFFFF0000u);
      s2 = fmaf(qa[k], snb[d0], fmaf(qb[k], snb[d0+1], s2));
    }
    float s3 = qrow[lane] * bk[hh*DHEAD + lane];
    s1 = wsum64(s1); s2 = wsum64(s2); s3 = wsum64(s3);
    if (lane == 0){ SQW[w16] = s1; SC[w16] = 0.125f * (s2 + s3); }
  }
}

// -------- prep (once): LN stats + bf16 copy, len-gated --------
__global__ __launch_bounds__(256) void k_prep(const float* __restrict__ seq,
    const int* __restrict__ lens, uint32_t* __restrict__ xbf,
    float* __restrict__ mstat, float* __restrict__ rstat){
  int gw = (blockIdx.x * 256 + threadIdx.x) >> 6;
  int lane = threadIdx.x & 63;
  int nb = gw >> 9, s = gw & 511;
  if (s >= lens[nb]) return;
  const float4* x4 = (const float4*)(seq + (size_t)gw * DMODEL);
  float4 v0 = x4[lane], v1 = x4[64 + lane], v2 = x4[128 + lane];
  float sm = v0.x+v0.y+v0.z+v0.w + v1.x+v1.y+v1.z+v1.w + v2.x+v2.y+v2.z+v2.w;
  float q = dot4f(v0,v0) + dot4f(v1,v1) + dot4f(v2,v2);
  sm = wsum64(sm); q = wsum64(q);
  float m = sm * (1.0f/DMODEL);
  float r = rsqrtf(q * (1.0f/DMODEL) - m*m + 1e-5f);
  if (lane == 0){ mstat[gw] = m; rstat[gw] = r; }
  uint32_t* o = xbf + (size_t)gw * 384;
  o[2*lane]       = bfpair(v0.x, v0.y);
  o[2*lane+1]     = bfpair(v0.z, v0.w);
  o[128+2*lane]   = bfpair(v1.x, v1.y);
  o[128+2*lane+1] = bfpair(v1.z, v1.w);
  o[256+2*lane]   = bfpair(v2.x, v2.y);
  o[256+2*lane+1] = bfpair(v2.z, v2.w);
}

// -------- MFMA attention (R8 proven) --------
__global__ __launch_bounds__(256) void k_attnM(const uint32_t* __restrict__ xbf,
    const int* __restrict__ lens, const uint32_t* __restrict__ QWbf,
    const float* __restrict__ SQW, const float* __restrict__ SC,
    const float* __restrict__ mstat, const float* __restrict__ rstat,
    float* __restrict__ Pacc, float* __restrict__ Pden,
    float* __restrict__ Pc, float* __restrict__ Pmx){
  __shared__ float er_lds[64*17];
  __shared__ float tmax[4][16], tsum[4][16], tcs[4][16], fls[4][16];
  int blk = blockIdx.x;
  int ch = blk & 7, nb = blk >> 3;
  int len = lens[nb];
  int s0 = ch * ROWCH;
  if (s0 >= len) return;
  int b = nb % NB;
  int tid = threadIdx.x, wid = tid >> 6, lane = tid & 63;
  int l15 = lane & 15, mg = lane >> 4;
  int r0 = s0 + wid * 16;

  const short8* ax = (const short8*)(xbf + ((size_t)(nb*SEQLEN + r0 + l15)) * 384) + mg;
  const short8* bq = (const short8*)(QWbf + ((size_t)(b*16 + l15)) * 384) + mg;
  f32x4 acc = {0.0f, 0.0f, 0.0f, 0.0f};
  #pragma unroll
  for (int kk = 0; kk < 24; ++kk)
    acc = __builtin_amdgcn_mfma_f32_16x16x32_bf16(ax[kk*4], bq[kk*4], acc, 0, 0, 0);
  float sqw = SQW[b*16 + l15], scc = SC[b*16 + l15];
  float sco[4];
  #pragma unroll
  for (int j = 0; j < 4; ++j){
    int s = r0 + mg*4 + j;
    float mm = mstat[(size_t)nb*SEQLEN + s];
    float v = rstat[(size_t)nb*SEQLEN + s] * (acc[j] - mm * sqw) + scc;
    sco[j] = (s < len) ? v : -3.0e38f;
  }
  float tm = fmaxf(fmaxf(sco[0], sco[1]), fmaxf(sco[2], sco[3]));
  tm = fmaxf(tm, __shfl_xor(tm, 16, 64));
  tm = fmaxf(tm, __shfl_xor(tm, 32, 64));
  float es = 0, cs = 0;
  #pragma unroll
  for (int j = 0; j < 4; ++j){
    int s = r0 + mg*4 + j;
    float e = (sco[j] > -1.0e37f) ? __expf(sco[j] - tm) : 0.0f;
    float rr = rstat[(size_t)nb*SEQLEN + s];
    float er = e * rr;
    er_lds[(wid*16 + mg*4 + j)*17 + l15] = er;
    es += e;
    cs = fmaf(er, mstat[(size_t)nb*SEQLEN + s], cs);
  }
  es += __shfl_xor(es, 16, 64); es += __shfl_xor(es, 32, 64);
  cs += __shfl_xor(cs, 16, 64); cs += __shfl_xor(cs, 32, 64);
  if (lane < 16){ tmax[wid][lane] = tm; tsum[wid][lane] = es; tcs[wid][lane] = cs; }
  __syncthreads();
  if (tid < 16){
    int hh = tid;
    float M = fmaxf(fmaxf(tmax[0][hh], tmax[1][hh]), fmaxf(tmax[2][hh], tmax[3][hh]));
    float D = 0, C = 0;
    #pragma unroll
    for (int w = 0; w < 4; ++w){
      float f = (tmax[w][hh] > -1.0e37f) ? __expf(tmax[w][hh] - M) : 0.0f;
      fls[w][hh] = f;
      D = fmaf(f, tsum[w][hh], D);
      C = fmaf(f, tcs[w][hh], C);
    }
    if (hh < NHEAD){
      Pmx[(size_t)blk*NHEAD + hh] = M;
      Pden[(size_t)blk*NHEAD + hh] = D;
      Pc[(size_t)blk*NHEAD + hh] = C;
    }
  }
  __syncthreads();
  #pragma unroll
  for (int t = 0; t < 4; ++t){
    int i = tid + t*256;
    int row = i >> 4, hh = i & 15;
    er_lds[row*17 + hh] *= fls[row >> 4][hh];
  }
  __syncthreads();

  int h0 = wid * 3;
  float a[3][12];
  #pragma unroll
  for (int j = 0; j < 3; ++j)
    #pragma unroll
    for (int c = 0; c < 12; ++c) a[j][c] = 0.0f;
  const uint32_t* xr0 = xbf + ((size_t)(nb*SEQLEN + s0)) * 384 + lane*6;
  int nrows = len - s0; if (nrows > ROWCH) nrows = ROWCH;
  for (int s = 0; s < nrows; ++s){
    const uint32_t* xr = xr0 + (size_t)s * 384;
    uint2 u01 = *(const uint2*)(xr);
    uint2 u23 = *(const uint2*)(xr + 2);
    uint2 u45 = *(const uint2*)(xr + 4);
    float e0 = er_lds[s*17 + h0], e1 = er_lds[s*17 + h0 + 1], e2 = er_lds[s*17 + h0 + 2];
    float x[12];
    x[0]  = __uint_as_float(u01.x << 16); x[1]  = __uint_as_float(u01.x & 0xFFFF0000u);
    x[2]  = __uint_as_float(u01.y << 16); x[3]  = __uint_as_float(u01.y & 0xFFFF0000u);
    x[4]  = __uint_as_float(u23.x << 16); x[5]  = __uint_as_float(u23.x & 0xFFFF0000u);
    x[6]  = __uint_as_float(u23.y << 16); x[7]  = __uint_as_float(u23.y & 0xFFFF0000u);
    x[8]  = __uint_as_float(u45.x << 16); x[9]  = __uint_as_float(u45.x & 0xFFFF0000u);
    x[10] = __uint_as_float(u45.y << 16); x[11] = __uint_as_float(u45.y & 0xFFFF0000u);
    #pragma unroll
    for (int c = 0; c < 12; ++c){
      a[0][c] = fmaf(e0, x[c], a[0][c]);
      a[1][c] = fmaf(e1, x[c], a[1][c]);
      a[2][c] = fmaf(e2, x[c], a[2][c]);
    }
  }
  #pragma unroll
  for (int j = 0; j < 3; ++j){
    float* p = Pacc + ((size_t)blk*NHEAD + h0 + j) * DMODEL + lane*12;
    #pragma unroll
    for (int c = 0; c < 12; c += 4)
      *(float4*)(p + c) = make_float4(a[j][c], a[j][c+1], a[j][c+2], a[j][c+3]);
  }
}

// -------- combine --------
__global__ __launch_bounds__(256) void k_comb(const float* __restrict__ Pacc,
    const float* __restrict__ Pden, const float* __restrict__ Pc,
    const float* __restrict__ Pmx, const int* __restrict__ lens,
    const float* __restrict__ snw, const float* __restrict__ snb,
    float* __restrict__ wsum){
  int tid = blockIdx.x * 256 + threadIdx.x;
  int d = tid % DMODEL;
  int t = tid / DMODEL;
  int h = t % NHEAD;
  int b = t / NHEAD;
  float vec = 0.0f, csum = 0.0f;
  #pragma unroll
  for (int n = 0; n < NDOM; ++n){
    int nb = n*NB + b;
    int len = lens[nb];
    int na = (len + ROWCH - 1) >> 6; if (na > NCH) na = NCH;
    size_t p0 = (size_t)(nb * NCH) * NHEAD + h;
    float M = -3.0e38f;
    for (int c = 0; c < na; ++c) M = fmaxf(M, Pmx[p0 + (size_t)c*NHEAD]);
    float D = 0, V = 0, C = 0;
    for (int c = 0; c < na; ++c){
      size_t pi = p0 + (size_t)c*NHEAD;
      float w = __expf(Pmx[pi] - M);
      D = fmaf(w, Pden[pi], D);
      V = fmaf(w, Pacc[pi*DMODEL + d], V);
      C = fmaf(w, Pc[pi], C);
    }
    float inv = 1.0f / D;
    vec = fmaf(V, inv, vec);
    csum = fmaf(C, inv, csum);
  }
  wsum[tid] = (vec - csum) * snw[d] + 3.0f * snb[d];
}

// -------- ctxsum --------
__global__ __launch_bounds__(256) void k_ctxv2(const float* __restrict__ wsum,
    const float* __restrict__ Wv, const float* __restrict__ bv, float* __restrict__ ctxsum){
  int gw = (blockIdx.x * 256 + threadIdx.x) >> 6;
  int lane = threadIdx.x & 63;
  int sl = lane & 7, g = lane >> 3;
  int bg = gw & 7; int j0 = (gw >> 3) * 4;
  int h = j0 >> 6;
  const float4* a4 = (const float4*)(wsum + ((size_t)(bg*8 + g) * NHEAD + h) * DMODEL);
  const float4* w0 = (const float4*)(Wv + (size_t)(j0+0) * DMODEL);
  const float4* w1 = (const float4*)(Wv + (size_t)(j0+1) * DMODEL);
  const float4* w2 = (const float4*)(Wv + (size_t)(j0+2) * DMODEL);
  const float4* w3 = (const float4*)(Wv + (size_t)(j0+3) * DMODEL);
  float acc0 = 0, acc1 = 0, acc2 = 0, acc3 = 0;
  #pragma unroll 4
  for (int i = 0; i < DMODEL/32; ++i){
    float4 av = a4[i*8 + sl];
    acc0 += dot4f(av, w0[i*8 + sl]);
    acc1 += dot4f(av, w1[i*8 + sl]);
    acc2 += dot4f(av, w2[i*8 + sl]);
    acc3 += dot4f(av, w3[i*8 + sl]);
  }
  #pragma unroll
  for (int o = 1; o <= 4; o <<= 1){
    acc0 += __shfl_xor(acc0, o, 64);
    acc1 += __shfl_xor(acc1, o, 64);
    acc2 += __shfl_xor(acc2, o, 64);
    acc3 += __shfl_xor(acc3, o, 64);
  }
  if (sl == 0){
    float4 bb = *(const float4*)(bv + j0);
    *(float4*)(ctxsum + (size_t)(bg*8 + g) * DMODEL + j0) =
      make_float4(acc0 + 3.0f*bb.x, acc1 + 3.0f*bb.y, acc2 + 3.0f*bb.z, acc3 + 3.0f*bb.w);
  }
}

// -------- gate + residual --------
__global__ __launch_bounds__(256) void k_gate2(const float* __restrict__ ctx,
    const float* __restrict__ sctx, const float* __restrict__ Wg,
    const float* __restrict__ gb, float* __restrict__ out){
  int gw = (blockIdx.x * 256 + threadIdx.x) >> 6;
  int lane = threadIdx.x & 63;
  int sl = lane & 7, g = lane >> 3;
  int bg = gw & 7; int j0 = (gw >> 3) * 4;
  int row = bg*8 + g;
  const float4* c4 = (const float4*)(ctx + (size_t)row * DMODEL);
  const float4* s4 = (const float4*)(sctx + (size_t)row * DMODEL);
  const float4* wr0 = (const float4*)(Wg + (size_t)(j0+0) * 2 * DMODEL);
  const float4* wr1 = (const float4*)(Wg + (size_t)(j0+1) * 2 * DMODEL);
  const float4* wr2 = (const float4*)(Wg + (size_t)(j0+2) * 2 * DMODEL);
  const float4* wr3 = (const float4*)(Wg + (size_t)(j0+3) * 2 * DMODEL);
  float acc0 = 0, acc1 = 0, acc2 = 0, acc3 = 0;
  #pragma unroll 4
  for (int i = 0; i < DMODEL/32; ++i){
    float4 cv = c4[i*8 + sl], sv = s4[i*8 + sl];
    acc0 += dot4f(cv, wr0[i*8 + sl]) + dot4f(sv, wr0[192 + i*8 + sl]);
    acc1 += dot4f(cv, wr1[i*8 + sl]) + dot4f(sv, wr1[192 + i*8 + sl]);
    acc2 += dot4f(cv, wr2[i*8 + sl]) + dot4f(sv, wr2[192 + i*8 + sl]);
    acc3 += dot4f(cv, wr3[i*8 + sl]) + dot4f(sv, wr3[192 + i*8 + sl]);
  }
  #pragma unroll
  for (int o = 1; o <= 4; o <<= 1){
    acc0 += __shfl_xor(acc0, o, 64);
    acc1 += __shfl_xor(acc1, o, 64);
    acc2 += __shfl_xor(acc2, o, 64);
    acc3 += __shfl_xor(acc3, o, 64);
  }
  if (sl == 0){
    size_t o = (size_t)row * DMODEL + j0;
    float4 bb = *(const float4*)(gb + j0);
    float4 cc = *(const float4*)(ctx + o);
    float4 ss = *(const float4*)(sctx + o);
    float4 v;
    v.x = cc.x + ss.x / (1.0f + __expf(-(acc0 + bb.x)));
    v.y = cc.y + ss.y / (1.0f + __expf(-(acc1 + bb.y)));
    v.z = cc.z + ss.z / (1.0f + __expf(-(acc2 + bb.z)));
    v.w = cc.w + ss.w / (1.0f + __expf(-(acc3 + bb.w)));
    *(float4*)(out + o) = v;
  }
}

// -------- classifier final dot --------
__global__ __launch_bounds__(256) void k_cls2(const float* __restrict__ h2,
    const float* __restrict__ w2, const float* __restrict__ b2, float* __restrict__ out){
  int b = blockIdx.x; int t = threadIdx.x;
  float acc = 0;
  for (int j = t; j < FFNH; j += 256) acc = fmaf(h2[(size_t)b*FFNH + j], w2[j], acc);
  acc = wsum64(acc);
  __shared__ float sh[4];
  if ((t & 63) == 0) sh[t >> 6] = acc;
  __syncthreads();
  if (t == 0) out[b] = sh[0] + sh[1] + sh[2] + sh[3] + b2[0];
}

extern "C" void kernel_launch(void* const* d_in, const int* in_sizes, int n_in,
                              void* d_out, int out_size, void* d_ws, size_t ws_size,
                              hipStream_t stream){
  const float* in_ctx = (const float*)d_in[0];
  const float* seq    = (const float*)d_in[1];
  const int*   lens   = (const int*)d_in[2];
  const float* qn_w   = (const float*)d_in[3];
  const float* qn_b   = (const float*)d_in[4];
  const float* sn_w   = (const float*)d_in[5];
  const float* sn_b   = (const float*)d_in[6];
  const float* in_w   = (const float*)d_in[7];
  const float* in_b   = (const float*)d_in[8];
  const float* out_w  = (const float*)d_in[9];
  const float* out_b  = (const float*)d_in[10];
  const float* gate_w = (const float*)d_in[11];
  const float* gate_b = (const float*)d_in[12];
  const float* fln_w  = (const float*)d_in[13];
  const float* fln_b  = (const float*)d_in[14];
  const float* fw1    = (const float*)d_in[15];
  const float* fb1    = (const float*)d_in[16];
  const float* fw2    = (const float*)d_in[17];
  const float* fb2    = (const float*)d_in[18];
  const float* on_w   = (const float*)d_in[19];
  const float* on_b   = (const float*)d_in[20];
  const float* cl_w   = (const float*)d_in[21];
  const float* cl_b   = (const float*)d_in[22];
  const float* cw1    = (const float*)d_in[23];
  const float* cb1    = (const float*)d_in[24];
  const float* cw2    = (const float*)d_in[25];
  const float* cb2    = (const float*)d_in[26];

  float* wsf = (float*)d_ws;
  size_t off = 0;
  auto alloc = [&](size_t n){ float* p = wsf + off; off += n; return p; };
  float* c0     = alloc((size_t)NB*DMODEL);
  float* c1     = alloc((size_t)NB*DMODEL);
  float* cmid   = alloc((size_t)NB*DMODEL);
  uint32_t* QWbf = (uint32_t*)alloc((size_t)NB*16*384);
  float* SQWb   = alloc((size_t)NB*16);
  float* SCb    = alloc((size_t)NB*16);
  uint32_t* xbf = (uint32_t*)alloc((size_t)NBROWS*SEQLEN*384);
  float* mstat  = alloc((size_t)NBROWS*SEQLEN);
  float* rstat  = alloc((size_t)NBROWS*SEQLEN);
  float* Pacc   = alloc((size_t)NBROWS*NCH*NHEAD*DMODEL);
  float* Pden   = alloc((size_t)NBROWS*NCH*NHEAD);
  float* Pc     = alloc((size_t)NBROWS*NCH*NHEAD);
  float* Pmx    = alloc((size_t)NBROWS*NCH*NHEAD);
  float* wsumb  = alloc((size_t)NB*NHEAD*DMODEL);
  float* ctxsum = alloc((size_t)NB*DMODEL);
  float* sctx   = alloc((size_t)NB*DMODEL);
  float* h0     = alloc((size_t)NB*DMODEL);
  float* h1     = alloc((size_t)NB*FFNH);
  (void)ws_size; (void)in_sizes; (void)n_in; (void)out_size;

  hipMemcpyAsync(c0, in_ctx, (size_t)NB*DMODEL*sizeof(float), hipMemcpyDeviceToDevice, stream);
  k_prep<<<(NBROWS*SEQLEN)/4, 256, 0, stream>>>(seq, lens, xbf, mstat, rstat);

  float* cur = c0; float* nxt = c1;
  for (int l = 0; l < NBLK; ++l){
    const float* Wq = in_w + (size_t)l * 3 * DMODEL * DMODEL;
    const float* Wk = Wq + (size_t)DMODEL * DMODEL;
    const float* Wv = Wq + (size_t)2 * DMODEL * DMODEL;
    const float* bq = in_b + (size_t)l * 3 * DMODEL;
    const float* bk = bq + DMODEL;
    const float* bv = bq + 2 * DMODEL;

    k_qhead<<<256, 256, 0, stream>>>(cur, qn_w + l*DMODEL, qn_b + l*DMODEL,
        Wq, bq, Wk, bk, sn_w + l*DMODEL, sn_b + l*DMODEL, QWbf, SQWb, SCb);
    k_attnM<<<NBROWS*NCH, 256, 0, stream>>>(xbf, lens, QWbf, SQWb, SCb, mstat, rstat, Pacc, Pden, Pc, Pmx);
    k_comb<<<(NB*NHEAD*DMODEL)/256, 256, 0, stream>>>(Pacc, Pden, Pc, Pmx, lens, sn_w + l*DMODEL, sn_b + l*DMODEL, wsumb);
    k_ctxv2<<<384, 256, 0, stream>>>(wsumb, Wv, bv, ctxsum);
    k_gemmW<DMODEL,DMODEL,2,false><<<384, 256, 0, stream>>>(ctxsum, out_w + (size_t)l*DMODEL*DMODEL, out_b + l*DMODEL, nullptr, sctx);
    k_gate2<<<384, 256, 0, stream>>>(cur, sctx, gate_w + (size_t)l*DMODEL*2*DMODEL, gate_b + l*DMODEL, cmid);
    k_ln<<<16, 256, 0, stream>>>(cmid, fln_w + l*DMODEL, fln_b + l*DMODEL, h0, NB);
    k_gemmW<DMODEL,FFNH,1,false><<<1536, 256, 0, stream>>>(h0, fw1 + (size_t)l*FFNH*DMODEL, fb1 + l*FFNH, nullptr, h1);
    k_gemmW<FFNH,DMODEL,0,true><<<384, 256, 0, stream>>>(h1, fw2 + (size_t)l*DMODEL*FFNH, fb2 + l*DMODEL, cmid, nxt);
    float* t = cur; cur = nxt; nxt = t;
  }

  k_ln2<<<16, 256, 0, stream>>>(cur, on_w, on_b, cl_w, cl_b, h0, NB);
  k_gemmW<DMODEL,FFNH,1,false><<<1536, 256, 0, stream>>>(h0, cw1, cb1, nullptr, h1);
  k_cls2<<<64, 256, 0, stream>>>(h1, cw2, cb2, (float*)d_out);
}